// Round 4
// baseline (215.913 us; speedup 1.0000x reference)
//
#include <hip/hip_runtime.h>

// loss = N * sum(x*x) - sum_j (colsum_j)^2, x: [8192][4096] f32 row-major.
// 3-stage atomic-free reduction (R4: stage-1 grid 512 -> 1024 blocks for
// latency hiding; R3 analysis: ~115us of dur_us is harness reset traffic
// (512MiB ws poison @87% peak + input restore), our kernels ~85us vs 25us
// ideal -> stage-1 was parallelism-starved at 2 blocks/CU).
//   s1: 1024 blocks, each owns 8 contiguous rows; per-block colsum partial
//       stored as plain float4 to ws[b*4096..]; sumsq partial to SS[b].
//   s2: 64 blocks; block reduces 64 columns over 1024 partials, squares -> CQ.
//   s3: 1 block combines SS[1024] and CQ[64] -> out.

#define NROWS 8192
#define NCOLS 4096

constexpr int BLOCK = 256;
constexpr int PB    = 1024;              // stage-1 blocks (4/CU, 16 waves/CU)
constexpr int RPB   = NROWS / PB;        // 8 rows per block
constexpr int CQB   = 64;                // stage-2 blocks
constexpr size_t P_ELEMS = (size_t)PB * NCOLS;
constexpr size_t SS_OFF  = P_ELEMS;          // [PB] floats
constexpr size_t CQ_OFF  = P_ELEMS + PB;     // [CQB] floats
constexpr size_t WS_NEEDED = (P_ELEMS + PB + CQB) * sizeof(float);

__global__ __launch_bounds__(BLOCK) void s1_partials(
    const float* __restrict__ x, float* __restrict__ ws)
{
    const int t = threadIdx.x, b = blockIdx.x;
    float4 cs[4];
    #pragma unroll
    for (int k = 0; k < 4; ++k) cs[k] = make_float4(0.f, 0.f, 0.f, 0.f);
    float ss = 0.f;

    const float* base = x + (size_t)b * RPB * NCOLS;   // contiguous 128KB slab
    #pragma unroll
    for (int rr = 0; rr < RPB; rr += 4) {              // 16 float4 loads in flight
        float4 v[16];
        #pragma unroll
        for (int r = 0; r < 4; ++r) {
            const float4* row = reinterpret_cast<const float4*>(
                base + (size_t)(rr + r) * NCOLS);
            #pragma unroll
            for (int k = 0; k < 4; ++k) v[r * 4 + k] = row[t + k * BLOCK];
        }
        #pragma unroll
        for (int k = 0; k < 16; ++k) {
            const int c = k & 3;
            cs[c].x += v[k].x; cs[c].y += v[k].y; cs[c].z += v[k].z; cs[c].w += v[k].w;
            ss += v[k].x * v[k].x + v[k].y * v[k].y + v[k].z * v[k].z + v[k].w * v[k].w;
        }
    }

    // plain coalesced stores of the block's column partial (no atomics)
    float4* P = reinterpret_cast<float4*>(ws) + (size_t)b * (NCOLS / 4);
    #pragma unroll
    for (int k = 0; k < 4; ++k) P[t + k * BLOCK] = cs[k];

    // block-reduce ss -> SS[b]
    #pragma unroll
    for (int off = 32; off > 0; off >>= 1) ss += __shfl_down(ss, off, 64);
    __shared__ float wss[BLOCK / 64];
    if ((t & 63) == 0) wss[t >> 6] = ss;
    __syncthreads();
    if (t == 0) ws[SS_OFF + b] = wss[0] + wss[1] + wss[2] + wss[3];
}

__global__ __launch_bounds__(BLOCK) void s2_colsq(
    const float* __restrict__ ws, float* __restrict__ wcq)
{
    const int t = threadIdx.x;
    const int tj = t & 63, tp = t >> 6;        // 64 cols x 4 p-groups
    const int j = blockIdx.x * 64 + tj;
    float c = 0.f;
    #pragma unroll 8
    for (int p = tp; p < PB; p += 4) c += ws[(size_t)p * NCOLS + j];
    __shared__ float part[4][64];
    part[tp][tj] = c;
    __syncthreads();
    if (t < 64) {                               // wave 0
        float cj = part[0][tj] + part[1][tj] + part[2][tj] + part[3][tj];
        float v = cj * cj;
        #pragma unroll
        for (int off = 32; off > 0; off >>= 1) v += __shfl_down(v, off, 64);
        if (tj == 0) wcq[blockIdx.x] = v;
    }
}

__global__ __launch_bounds__(BLOCK) void s3_final(
    const float* __restrict__ ws, float* __restrict__ out)
{
    const int t = threadIdx.x;
    float ssp = ws[SS_OFF + t] + ws[SS_OFF + 256 + t]
              + ws[SS_OFF + 512 + t] + ws[SS_OFF + 768 + t];
    float cqp = (t < CQB) ? ws[CQ_OFF + t] : 0.f;
    #pragma unroll
    for (int off = 32; off > 0; off >>= 1) {
        ssp += __shfl_down(ssp, off, 64);
        cqp += __shfl_down(cqp, off, 64);
    }
    __shared__ float wa[BLOCK / 64], wb[BLOCK / 64];
    if ((t & 63) == 0) { wa[t >> 6] = ssp; wb[t >> 6] = cqp; }
    __syncthreads();
    if (t == 0) {
        float sstot = wa[0] + wa[1] + wa[2] + wa[3];
        float cqtot = wb[0] + wb[1] + wb[2] + wb[3];
        out[0] = (float)NROWS * sstot - cqtot;
    }
}

// ---- fallback (R1 atomic version, known-correct) for small ws ----
__global__ __launch_bounds__(BLOCK) void fb_partial(
    const float* __restrict__ x, float* __restrict__ ws)
{
    const int t = threadIdx.x;
    float4 cs[4];
    #pragma unroll
    for (int k = 0; k < 4; ++k) cs[k] = make_float4(0.f, 0.f, 0.f, 0.f);
    float ss = 0.f;
    for (int r = blockIdx.x; r < NROWS; r += gridDim.x) {
        const float4* row = reinterpret_cast<const float4*>(x + (size_t)r * NCOLS);
        #pragma unroll
        for (int k = 0; k < 4; ++k) {
            float4 v = row[t + k * BLOCK];
            cs[k].x += v.x; cs[k].y += v.y; cs[k].z += v.z; cs[k].w += v.w;
            ss += v.x * v.x + v.y * v.y + v.z * v.z + v.w * v.w;
        }
    }
    #pragma unroll
    for (int k = 0; k < 4; ++k) {
        const int c = 4 * (t + k * BLOCK);
        atomicAdd(&ws[c + 0], cs[k].x);
        atomicAdd(&ws[c + 1], cs[k].y);
        atomicAdd(&ws[c + 2], cs[k].z);
        atomicAdd(&ws[c + 3], cs[k].w);
    }
    #pragma unroll
    for (int off = 32; off > 0; off >>= 1) ss += __shfl_down(ss, off, 64);
    __shared__ float wss[BLOCK / 64];
    if ((t & 63) == 0) wss[t >> 6] = ss;
    __syncthreads();
    if (t == 0) {
        float s = 0.f;
        #pragma unroll
        for (int w = 0; w < BLOCK / 64; ++w) s += wss[w];
        atomicAdd(&ws[NCOLS], s);
    }
}

__global__ __launch_bounds__(BLOCK) void fb_finalize(
    const float* __restrict__ ws, float* __restrict__ out)
{
    const int t = threadIdx.x;
    float acc = 0.f;
    #pragma unroll
    for (int k = 0; k < NCOLS / BLOCK; ++k) {
        float c = ws[t + k * BLOCK];
        acc += c * c;
    }
    #pragma unroll
    for (int off = 32; off > 0; off >>= 1) acc += __shfl_down(acc, off, 64);
    __shared__ float wss[BLOCK / 64];
    if ((t & 63) == 0) wss[t >> 6] = acc;
    __syncthreads();
    if (t == 0) {
        float colsq = 0.f;
        #pragma unroll
        for (int w = 0; w < BLOCK / 64; ++w) colsq += wss[w];
        out[0] = (float)NROWS * ws[NCOLS] - colsq;
    }
}

extern "C" void kernel_launch(void* const* d_in, const int* in_sizes, int n_in,
                              void* d_out, int out_size, void* d_ws, size_t ws_size,
                              hipStream_t stream) {
    const float* x = (const float*)d_in[0];
    float* ws  = (float*)d_ws;
    float* out = (float*)d_out;

    if (ws_size >= WS_NEEDED) {
        // atomic-free path; every ws element read is written first (no memset)
        s1_partials<<<PB, BLOCK, 0, stream>>>(x, ws);
        s2_colsq<<<CQB, BLOCK, 0, stream>>>(ws, ws + CQ_OFF);
        s3_final<<<1, BLOCK, 0, stream>>>(ws, out);
    } else {
        hipMemsetAsync(ws, 0, (NCOLS + 1) * sizeof(float), stream);
        fb_partial<<<512, BLOCK, 0, stream>>>(x, ws);
        fb_finalize<<<1, BLOCK, 0, stream>>>(ws, out);
    }
}

// Round 5
// 196.719 us; speedup vs baseline: 1.0976x; 1.0976x over previous
//
#include <hip/hip_runtime.h>

// loss = N * sum(x*x) - sum_j (colsum_j)^2, x: [8192][4096] f32 row-major.
// 3-stage atomic-free reduction. R5 = revert to best-measured R3 config
// (PB=512): R3->R4 A/B showed PB=1024 gains nothing (s1 not latency-bound
// at 2 blocks/CU) and costs extra partial traffic. Timed region is ~80%
// harness reset (512MiB ws poison @87% HBM peak + input restore + tiny
// fills); our controllable portion ~35-40us vs ~30us mandatory floor.
//   s1: 512 blocks x 16 rows; block-reduced colsum partial -> ws[b*4096..],
//       sumsq partial -> SS[b]. 16 float4 loads in flight per wave.
//   s2: 64 blocks; 64 cols x 4 p-groups over 512 partials, square -> CQ.
//   s3: 1 block combines SS[512] + CQ[64] -> out.

#define NROWS 8192
#define NCOLS 4096

constexpr int BLOCK = 256;
constexpr int PB    = 512;               // 2 blocks/CU, 8 waves/CU (best A/B)
constexpr int RPB   = NROWS / PB;        // 16 rows per block
constexpr int CQB   = 64;
constexpr size_t P_ELEMS = (size_t)PB * NCOLS;
constexpr size_t SS_OFF  = P_ELEMS;
constexpr size_t CQ_OFF  = P_ELEMS + PB;
constexpr size_t WS_NEEDED = (P_ELEMS + PB + CQB) * sizeof(float);

__global__ __launch_bounds__(BLOCK) void s1_partials(
    const float* __restrict__ x, float* __restrict__ ws)
{
    const int t = threadIdx.x, b = blockIdx.x;
    float4 cs[4];
    #pragma unroll
    for (int k = 0; k < 4; ++k) cs[k] = make_float4(0.f, 0.f, 0.f, 0.f);
    float ss = 0.f;

    const float* base = x + (size_t)b * RPB * NCOLS;   // contiguous 256KB slab
    #pragma unroll
    for (int rr = 0; rr < RPB; rr += 4) {              // 16 float4 loads in flight
        float4 v[16];
        #pragma unroll
        for (int r = 0; r < 4; ++r) {
            const float4* row = reinterpret_cast<const float4*>(
                base + (size_t)(rr + r) * NCOLS);
            #pragma unroll
            for (int k = 0; k < 4; ++k) v[r * 4 + k] = row[t + k * BLOCK];
        }
        #pragma unroll
        for (int k = 0; k < 16; ++k) {
            const int c = k & 3;
            cs[c].x += v[k].x; cs[c].y += v[k].y; cs[c].z += v[k].z; cs[c].w += v[k].w;
            ss += v[k].x * v[k].x + v[k].y * v[k].y + v[k].z * v[k].z + v[k].w * v[k].w;
        }
    }

    // plain coalesced stores of the block's column partial (no atomics)
    float4* P = reinterpret_cast<float4*>(ws) + (size_t)b * (NCOLS / 4);
    #pragma unroll
    for (int k = 0; k < 4; ++k) P[t + k * BLOCK] = cs[k];

    // block-reduce ss -> SS[b]
    #pragma unroll
    for (int off = 32; off > 0; off >>= 1) ss += __shfl_down(ss, off, 64);
    __shared__ float wss[BLOCK / 64];
    if ((t & 63) == 0) wss[t >> 6] = ss;
    __syncthreads();
    if (t == 0) ws[SS_OFF + b] = wss[0] + wss[1] + wss[2] + wss[3];
}

__global__ __launch_bounds__(BLOCK) void s2_colsq(
    const float* __restrict__ ws, float* __restrict__ wcq)
{
    const int t = threadIdx.x;
    const int tj = t & 63, tp = t >> 6;        // 64 cols x 4 p-groups
    const int j = blockIdx.x * 64 + tj;
    float c = 0.f;
    #pragma unroll 16
    for (int p = tp; p < PB; p += 4) c += ws[(size_t)p * NCOLS + j];
    __shared__ float part[4][64];
    part[tp][tj] = c;
    __syncthreads();
    if (t < 64) {                               // wave 0
        float cj = part[0][tj] + part[1][tj] + part[2][tj] + part[3][tj];
        float v = cj * cj;
        #pragma unroll
        for (int off = 32; off > 0; off >>= 1) v += __shfl_down(v, off, 64);
        if (tj == 0) wcq[blockIdx.x] = v;
    }
}

__global__ __launch_bounds__(BLOCK) void s3_final(
    const float* __restrict__ ws, float* __restrict__ out)
{
    const int t = threadIdx.x;
    float ssp = ws[SS_OFF + t] + ws[SS_OFF + BLOCK + t];
    float cqp = (t < CQB) ? ws[CQ_OFF + t] : 0.f;
    #pragma unroll
    for (int off = 32; off > 0; off >>= 1) {
        ssp += __shfl_down(ssp, off, 64);
        cqp += __shfl_down(cqp, off, 64);
    }
    __shared__ float wa[BLOCK / 64], wb[BLOCK / 64];
    if ((t & 63) == 0) { wa[t >> 6] = ssp; wb[t >> 6] = cqp; }
    __syncthreads();
    if (t == 0) {
        float sstot = wa[0] + wa[1] + wa[2] + wa[3];
        float cqtot = wb[0] + wb[1] + wb[2] + wb[3];
        out[0] = (float)NROWS * sstot - cqtot;
    }
}

// ---- fallback (R1 atomic version, known-correct) for small ws ----
__global__ __launch_bounds__(BLOCK) void fb_partial(
    const float* __restrict__ x, float* __restrict__ ws)
{
    const int t = threadIdx.x;
    float4 cs[4];
    #pragma unroll
    for (int k = 0; k < 4; ++k) cs[k] = make_float4(0.f, 0.f, 0.f, 0.f);
    float ss = 0.f;
    for (int r = blockIdx.x; r < NROWS; r += gridDim.x) {
        const float4* row = reinterpret_cast<const float4*>(x + (size_t)r * NCOLS);
        #pragma unroll
        for (int k = 0; k < 4; ++k) {
            float4 v = row[t + k * BLOCK];
            cs[k].x += v.x; cs[k].y += v.y; cs[k].z += v.z; cs[k].w += v.w;
            ss += v.x * v.x + v.y * v.y + v.z * v.z + v.w * v.w;
        }
    }
    #pragma unroll
    for (int k = 0; k < 4; ++k) {
        const int c = 4 * (t + k * BLOCK);
        atomicAdd(&ws[c + 0], cs[k].x);
        atomicAdd(&ws[c + 1], cs[k].y);
        atomicAdd(&ws[c + 2], cs[k].z);
        atomicAdd(&ws[c + 3], cs[k].w);
    }
    #pragma unroll
    for (int off = 32; off > 0; off >>= 1) ss += __shfl_down(ss, off, 64);
    __shared__ float wss[BLOCK / 64];
    if ((t & 63) == 0) wss[t >> 6] = ss;
    __syncthreads();
    if (t == 0) {
        float s = 0.f;
        #pragma unroll
        for (int w = 0; w < BLOCK / 64; ++w) s += wss[w];
        atomicAdd(&ws[NCOLS], s);
    }
}

__global__ __launch_bounds__(BLOCK) void fb_finalize(
    const float* __restrict__ ws, float* __restrict__ out)
{
    const int t = threadIdx.x;
    float acc = 0.f;
    #pragma unroll
    for (int k = 0; k < NCOLS / BLOCK; ++k) {
        float c = ws[t + k * BLOCK];
        acc += c * c;
    }
    #pragma unroll
    for (int off = 32; off > 0; off >>= 1) acc += __shfl_down(acc, off, 64);
    __shared__ float wss[BLOCK / 64];
    if ((t & 63) == 0) wss[t >> 6] = acc;
    __syncthreads();
    if (t == 0) {
        float colsq = 0.f;
        #pragma unroll
        for (int w = 0; w < BLOCK / 64; ++w) colsq += wss[w];
        out[0] = (float)NROWS * ws[NCOLS] - colsq;
    }
}

extern "C" void kernel_launch(void* const* d_in, const int* in_sizes, int n_in,
                              void* d_out, int out_size, void* d_ws, size_t ws_size,
                              hipStream_t stream) {
    const float* x = (const float*)d_in[0];
    float* ws  = (float*)d_ws;
    float* out = (float*)d_out;

    if (ws_size >= WS_NEEDED) {
        // atomic-free path; every ws element read is written first (no memset)
        s1_partials<<<PB, BLOCK, 0, stream>>>(x, ws);
        s2_colsq<<<CQB, BLOCK, 0, stream>>>(ws, ws + CQ_OFF);
        s3_final<<<1, BLOCK, 0, stream>>>(ws, out);
    } else {
        hipMemsetAsync(ws, 0, (NCOLS + 1) * sizeof(float), stream);
        fb_partial<<<512, BLOCK, 0, stream>>>(x, ws);
        fb_finalize<<<1, BLOCK, 0, stream>>>(ws, out);
    }
}